// Round 1
// baseline (12060.451 us; speedup 1.0000x reference)
//
#include <hip/hip_runtime.h>
#include <math.h>

#define NBLK 500
#define NTHR 256
#define TSTEPS 48

// workspace layout (float offsets)
#define OFF_WIH0T 0                         // [512][1024]
#define OFF_WHH0T (OFF_WIH0T + 512*1024)    // [256][1024]
#define OFF_WIH1T (OFF_WHH0T + 256*1024)    // [256][1024]
#define OFF_WHH1T (OFF_WIH1T + 256*1024)    // [256][1024]
#define OFF_BSUM0 (OFF_WHH1T + 256*1024)    // [1024]
#define OFF_BSUM1 (OFF_BSUM0 + 1024)        // [1024]
#define OFF_G0P   (OFF_BSUM1 + 1024)        // [3][64][1024]
#define OFF_G1P   (OFF_G0P + 3*64*1024)     // [2][64][1024]
#define OFF_H0    (OFF_G1P + 2*64*1024)     // [64][256]
#define OFF_H1    (OFF_H0 + 64*256)         // [64][256]
#define OFF_C0    (OFF_H1 + 64*256)         // [2][64][256] (double buffered)
#define OFF_C1    (OFF_C0 + 2*64*256)       // [64][256]
#define OFF_FLOAT_END (OFF_C1 + 64*256)
// then: argkey u64[2][64] padded to 64B stride (1024 u64 slots), then bar u32[2]

// ---- coherent (L2-bypassing, device-visible) accessors for cross-block data ----
__device__ __forceinline__ float ld_coh(const float* p) {
  return __hip_atomic_load((float*)p, __ATOMIC_RELAXED, __HIP_MEMORY_SCOPE_AGENT);
}
__device__ __forceinline__ void st_coh(float* p, float v) {
  __hip_atomic_store(p, v, __ATOMIC_RELAXED, __HIP_MEMORY_SCOPE_AGENT);
}
__device__ __forceinline__ unsigned long long ld_coh64(const unsigned long long* p) {
  return __hip_atomic_load((unsigned long long*)p, __ATOMIC_RELAXED, __HIP_MEMORY_SCOPE_AGENT);
}
__device__ __forceinline__ void st_coh64(unsigned long long* p, unsigned long long v) {
  __hip_atomic_store(p, v, __ATOMIC_RELAXED, __HIP_MEMORY_SCOPE_AGENT);
}
__device__ __forceinline__ float sigf(float x) { return 1.0f / (1.0f + expf(-x)); }

// grid barrier: release-only arrival (no L2 invalidate -> weights stay L2-cached).
// Sound because ALL cross-block data moves through sc-coherent (atomic relaxed agent)
// loads/stores which hit the coherence point directly; the RELEASE fetch_add drains
// vmcnt so producers' coherent stores are globally visible before arrival counts.
__device__ __forceinline__ void gsync(unsigned* cnt, unsigned* gen, unsigned& mygen) {
  __syncthreads();
  if (threadIdx.x == 0) {
    unsigned prev = __hip_atomic_fetch_add(cnt, 1u, __ATOMIC_RELEASE, __HIP_MEMORY_SCOPE_AGENT);
    if (prev == (unsigned)(NBLK - 1)) {
      __hip_atomic_store(cnt, 0u, __ATOMIC_RELAXED, __HIP_MEMORY_SCOPE_AGENT);
      __hip_atomic_store(gen, mygen + 1u, __ATOMIC_RELEASE, __HIP_MEMORY_SCOPE_AGENT);
    } else {
      while (__hip_atomic_load(gen, __ATOMIC_RELAXED, __HIP_MEMORY_SCOPE_AGENT) <= mygen) {
        __builtin_amdgcn_s_sleep(2);
      }
    }
  }
  ++mygen;
  __asm__ __volatile__("" ::: "memory");
  __syncthreads();
}

// ---- init: h/c initial states, bias sums, argmax keys, barrier ----
__global__ void lstm_init_kernel(const float* enc, const float* Wh, const float* bh,
                                 const float* Wc, const float* bc,
                                 const float* bih0, const float* bhh0,
                                 const float* bih1, const float* bhh1,
                                 float* ws, unsigned long long* argkey, unsigned* bar) {
  const int tid = threadIdx.x, blk = blockIdx.x;
  if (blk < 64) {
    __shared__ float el[256];
    el[tid] = enc[blk * 256 + tid];
    __syncthreads();
    const float4* el4 = (const float4*)el;
    const float4* wh4 = (const float4*)(Wh + tid * 256);
    const float4* wc4 = (const float4*)(Wc + tid * 256);
    float ah = bh[tid], ac = bc[tid];
#pragma unroll 4
    for (int f = 0; f < 64; ++f) {
      float4 x = el4[f], a = wh4[f], b = wc4[f];
      ah = fmaf(a.x, x.x, fmaf(a.y, x.y, fmaf(a.z, x.z, fmaf(a.w, x.w, ah))));
      ac = fmaf(b.x, x.x, fmaf(b.y, x.y, fmaf(b.z, x.z, fmaf(b.w, x.w, ac))));
    }
    ws[OFF_H0 + blk * 256 + tid] = ah;
    ws[OFF_H1 + blk * 256 + tid] = ah;
    ws[OFF_C0 + blk * 256 + tid] = ac;   // parity 0
    ws[OFF_C1 + blk * 256 + tid] = ac;
  } else {
    for (int g = tid; g < 1024; g += 256) {
      ws[OFF_BSUM0 + g] = bih0[g] + bhh0[g];
      ws[OFF_BSUM1 + g] = bih1[g] + bhh1[g];
    }
    for (int i = tid; i < 1024; i += 256) argkey[i] = 0ull;
    if (tid < 2) bar[tid] = 0u;
  }
}

// ---- transpose gate weights to [k][1024] so gate dots are lane-coalesced ----
__global__ void lstm_transpose_kernel(const float* Wih0, const float* Whh0,
                                      const float* Wih1, const float* Whh1, float* ws) {
  __shared__ float t[64][65];
  const int blk = blockIdx.x, tid = threadIdx.x;
  const float* src; float* dst; int C; int tile;
  if (blk < 128)      { src = Wih0; dst = ws + OFF_WIH0T; C = 512; tile = blk; }
  else if (blk < 192) { src = Whh0; dst = ws + OFF_WHH0T; C = 256; tile = blk - 128; }
  else if (blk < 256) { src = Wih1; dst = ws + OFF_WIH1T; C = 256; tile = blk - 192; }
  else                { src = Whh1; dst = ws + OFF_WHH1T; C = 256; tile = blk - 256; }
  const int tpr = C >> 6;
  const int r0 = (tile / tpr) << 6, c0 = (tile % tpr) << 6;
  const int c = tid & 63, w = tid >> 6;
  for (int p = 0; p < 16; ++p) { int r = p * 4 + w; t[r][c] = src[(size_t)(r0 + r) * C + c0 + c]; }
  __syncthreads();
  for (int p = 0; p < 16; ++p) { int cc = p * 4 + w; dst[(size_t)(c0 + cc) * 1024 + r0 + c] = t[c][cc]; }
}

// shared dot: 256-step K, 4 batch accumulators, weights coalesced over lanes
__device__ __forceinline__ void dot256(const float* wp, const float4* xl,
                                       float& a0, float& a1, float& a2, float& a3) {
  a0 = a1 = a2 = a3 = 0.f;
#pragma unroll 8
  for (int k = 0; k < 256; ++k) {
    float wv = wp[(size_t)k * 1024];
    float4 x = xl[k];
    a0 = fmaf(wv, x.x, a0); a1 = fmaf(wv, x.y, a1);
    a2 = fmaf(wv, x.z, a2); a3 = fmaf(wv, x.w, a3);
  }
}

__global__ __launch_bounds__(256, 2) void lstm_decode_kernel(
    const float* __restrict__ emb, const float* __restrict__ Wout,
    const float* __restrict__ bout, const int* __restrict__ sosp,
    const int* __restrict__ eosp, float* __restrict__ ws,
    unsigned long long* __restrict__ argkey, unsigned* __restrict__ bar,
    int* __restrict__ out) {
  const int tid = threadIdx.x;
  const int blk = blockIdx.x;
  __shared__ int tok_s[64];
  __shared__ unsigned long long done_s;
  __shared__ int alldone_s;
  __shared__ union {
    float x4[256 * 4];   // P1/P2: staged x transposed [k][4b]
    struct {             // P3b: Wout chunk [64k][64v] (xor-swizzled), h1 [64b][64k] (xor-swizzled)
      float w[64 * 64];
      float h[64 * 64];
      unsigned long long red[4][64];
    } c;
  } sm;
  unsigned* cnt = bar; unsigned* gen = bar + 1;
  unsigned mygen = 0;
  const int eos = *eosp;
  const int sos = *sosp;

  for (int t = 0;; ++t) {
    // ---------- preamble: consume step t-1 argmax, update done state, emit token ----------
    if (t == 0) {
      if (tid < 64) tok_s[tid] = sos;
      if (tid == 0) { done_s = 0ull; alldone_s = 0; }
    } else {
      if (tid < 64) {
        unsigned long long key = ld_coh64(&argkey[(((t - 1) & 1) * 64 + tid) * 8]);
        int v = (int)(~(unsigned)key);
        int outv = alldone_s ? 0 : v;                    // all_done BEFORE this step's update
        if (blk == 0) out[tid * TSTEPS + (t - 1)] = outv;
        bool nd = (((done_s >> tid) & 1ull) != 0ull) || (outv == eos);
        unsigned long long m = __ballot(nd);
        if (tid == 0) { done_s = m; if (m == ~0ull) alldone_s = 1; }
        tok_s[tid] = outv;                               // emb[0] is the zero row -> matches ref
      }
    }
    if (t == TSTEPS) break;
    __syncthreads();

    // ---------- P1: layer-0 gate partials. blocks: 16 bgroups x 4 quarters x 3 k-slices ----------
    if (blk < 192) {
      const int ks = blk % 3;
      const int q  = (blk / 3) & 3;
      const int bg = blk / 12;
      float hv[4];
      if (ks < 2) {
        const int kofs = ks * 256 + tid;
#pragma unroll
        for (int j = 0; j < 4; ++j)
          hv[j] = emb[(size_t)tok_s[bg * 4 + j] * 512 + kofs];
      } else {
#pragma unroll
        for (int j = 0; j < 4; ++j)
          hv[j] = ld_coh(&ws[OFF_H0 + (bg * 4 + j) * 256 + tid]);
      }
      ((float4*)sm.x4)[tid] = make_float4(hv[0], hv[1], hv[2], hv[3]);
      __syncthreads();
      const float* wp = ws + (ks == 0 ? OFF_WIH0T
                              : ks == 1 ? (OFF_WIH0T + 256 * 1024)
                                        : OFF_WHH0T) + (q * 256 + tid);
      float a0, a1, a2, a3;
      dot256(wp, (const float4*)sm.x4, a0, a1, a2, a3);
      const int g = q * 256 + tid;
      st_coh(&ws[OFF_G0P + (ks * 64 + bg * 4 + 0) * 1024 + g], a0);
      st_coh(&ws[OFF_G0P + (ks * 64 + bg * 4 + 1) * 1024 + g], a1);
      st_coh(&ws[OFF_G0P + (ks * 64 + bg * 4 + 2) * 1024 + g], a2);
      st_coh(&ws[OFF_G0P + (ks * 64 + bg * 4 + 3) * 1024 + g], a3);
    }
    gsync(cnt, gen, mygen);

    // ---------- P2: h0/c0 update (redundant per q) + layer-1 gate partials ----------
    if (blk < 128) {
      const int ks = blk & 1, q = (blk >> 1) & 3, bg = blk >> 3;
      float hv[4];
      if (ks == 0) {
#pragma unroll
        for (int j = 0; j < 4; ++j) {
          const int b = bg * 4 + j;
          const float* g0 = ws + OFF_G0P;
          float gi = ld_coh(&g0[(b) * 1024 + tid]) + ld_coh(&g0[(64 + b) * 1024 + tid]) +
                     ld_coh(&g0[(128 + b) * 1024 + tid]) + ws[OFF_BSUM0 + tid];
          float gf = ld_coh(&g0[(b) * 1024 + 256 + tid]) + ld_coh(&g0[(64 + b) * 1024 + 256 + tid]) +
                     ld_coh(&g0[(128 + b) * 1024 + 256 + tid]) + ws[OFF_BSUM0 + 256 + tid];
          float gg = ld_coh(&g0[(b) * 1024 + 512 + tid]) + ld_coh(&g0[(64 + b) * 1024 + 512 + tid]) +
                     ld_coh(&g0[(128 + b) * 1024 + 512 + tid]) + ws[OFF_BSUM0 + 512 + tid];
          float go = ld_coh(&g0[(b) * 1024 + 768 + tid]) + ld_coh(&g0[(64 + b) * 1024 + 768 + tid]) +
                     ld_coh(&g0[(128 + b) * 1024 + 768 + tid]) + ws[OFF_BSUM0 + 768 + tid];
          float c  = ld_coh(&ws[OFF_C0 + (t & 1) * 16384 + b * 256 + tid]);
          float cn = sigf(gf) * c + sigf(gi) * tanhf(gg);
          float hn = sigf(go) * tanhf(cn);
          if (q == 0) {
            st_coh(&ws[OFF_H0 + b * 256 + tid], hn);
            st_coh(&ws[OFF_C0 + ((t + 1) & 1) * 16384 + b * 256 + tid], cn);
          }
          hv[j] = hn;
        }
      } else {
#pragma unroll
        for (int j = 0; j < 4; ++j)
          hv[j] = ld_coh(&ws[OFF_H1 + (bg * 4 + j) * 256 + tid]);
      }
      ((float4*)sm.x4)[tid] = make_float4(hv[0], hv[1], hv[2], hv[3]);
      __syncthreads();
      const float* wp = ws + (ks == 0 ? OFF_WIH1T : OFF_WHH1T) + (q * 256 + tid);
      float a0, a1, a2, a3;
      dot256(wp, (const float4*)sm.x4, a0, a1, a2, a3);
      const int g = q * 256 + tid;
      st_coh(&ws[OFF_G1P + (ks * 64 + bg * 4 + 0) * 1024 + g], a0);
      st_coh(&ws[OFF_G1P + (ks * 64 + bg * 4 + 1) * 1024 + g], a1);
      st_coh(&ws[OFF_G1P + (ks * 64 + bg * 4 + 2) * 1024 + g], a2);
      st_coh(&ws[OFF_G1P + (ks * 64 + bg * 4 + 3) * 1024 + g], a3);
    }
    gsync(cnt, gen, mygen);

    // ---------- P3a: h1/c1 update (64 blocks) + reset next-parity argmax keys ----------
    if (blk < 64) {
      const int b = blk;
      const float* g1 = ws + OFF_G1P;
      float gi = ld_coh(&g1[(b) * 1024 + tid]) + ld_coh(&g1[(64 + b) * 1024 + tid]) + ws[OFF_BSUM1 + tid];
      float gf = ld_coh(&g1[(b) * 1024 + 256 + tid]) + ld_coh(&g1[(64 + b) * 1024 + 256 + tid]) + ws[OFF_BSUM1 + 256 + tid];
      float gg = ld_coh(&g1[(b) * 1024 + 512 + tid]) + ld_coh(&g1[(64 + b) * 1024 + 512 + tid]) + ws[OFF_BSUM1 + 512 + tid];
      float go = ld_coh(&g1[(b) * 1024 + 768 + tid]) + ld_coh(&g1[(64 + b) * 1024 + 768 + tid]) + ws[OFF_BSUM1 + 768 + tid];
      float c  = ld_coh(&ws[OFF_C1 + b * 256 + tid]);
      float cn = sigf(gf) * c + sigf(gi) * tanhf(gg);
      float hn = sigf(go) * tanhf(cn);
      st_coh(&ws[OFF_C1 + b * 256 + tid], cn);
      st_coh(&ws[OFF_H1 + b * 256 + tid], hn);
    }
    if (blk == 0 && tid < 64) st_coh64(&argkey[(((t + 1) & 1) * 64 + tid) * 8], 0ull);
    gsync(cnt, gen, mygen);

    // ---------- P3b: logits (all 500 blocks, 64 vocab rows each) + argmax ----------
    {
      const int v_col = tid >> 4, b_row = tid & 15;
      float acc[4][4];
#pragma unroll
      for (int i = 0; i < 4; ++i)
#pragma unroll
        for (int j = 0; j < 4; ++j) acc[i][j] = 0.f;

      for (int kc = 0; kc < 4; ++kc) {
        __syncthreads();
        // stage: Wout chunk transposed into [k][v] with xor swizzle; h1 as [b][k] xor-swizzled
#pragma unroll
        for (int p = 0; p < 4; ++p) {
          const int idx = p * 256 + tid;
          const int r = idx >> 4, cq = idx & 15;          // r: v-row / b-row, cq: k-quad
          const float4 wv = *(const float4*)&Wout[(size_t)(blk * 64 + r) * 256 + kc * 64 + cq * 4];
          const int rl = r >> 2, rm = r & 3, k0 = cq * 4;
          sm.c.w[(k0 + 0) * 64 + ((rl ^ ((k0 + 0) & 15)) << 2) + rm] = wv.x;
          sm.c.w[(k0 + 1) * 64 + ((rl ^ ((k0 + 1) & 15)) << 2) + rm] = wv.y;
          sm.c.w[(k0 + 2) * 64 + ((rl ^ ((k0 + 2) & 15)) << 2) + rm] = wv.z;
          sm.c.w[(k0 + 3) * 64 + ((rl ^ ((k0 + 3) & 15)) << 2) + rm] = wv.w;
          const unsigned long long* hp =
              (const unsigned long long*)&ws[OFF_H1 + r * 256 + kc * 64 + cq * 4];
          float4 hv4;
          ((unsigned long long*)&hv4)[0] = ld_coh64(&hp[0]);
          ((unsigned long long*)&hv4)[1] = ld_coh64(&hp[1]);
          *(float4*)&sm.c.h[r * 64 + ((cq ^ (rl & 15)) << 2)] = hv4;
        }
        __syncthreads();
#pragma unroll 4
        for (int k4 = 0; k4 < 16; ++k4) {
          const int kb = k4 * 4;
          const float4 w0 = *(const float4*)&sm.c.w[(kb + 0) * 64 + ((v_col ^ ((kb + 0) & 15)) << 2)];
          const float4 w1 = *(const float4*)&sm.c.w[(kb + 1) * 64 + ((v_col ^ ((kb + 1) & 15)) << 2)];
          const float4 w2 = *(const float4*)&sm.c.w[(kb + 2) * 64 + ((v_col ^ ((kb + 2) & 15)) << 2)];
          const float4 w3 = *(const float4*)&sm.c.w[(kb + 3) * 64 + ((v_col ^ ((kb + 3) & 15)) << 2)];
#pragma unroll
          for (int j = 0; j < 4; ++j) {
            const int b = b_row * 4 + j;
            const float4 hv = *(const float4*)&sm.c.h[b * 64 + ((k4 ^ ((b >> 2) & 15)) << 2)];
            acc[0][j] = fmaf(w0.x, hv.x, fmaf(w1.x, hv.y, fmaf(w2.x, hv.z, fmaf(w3.x, hv.w, acc[0][j]))));
            acc[1][j] = fmaf(w0.y, hv.x, fmaf(w1.y, hv.y, fmaf(w2.y, hv.z, fmaf(w3.y, hv.w, acc[1][j]))));
            acc[2][j] = fmaf(w0.z, hv.x, fmaf(w1.z, hv.y, fmaf(w2.z, hv.z, fmaf(w3.z, hv.w, acc[2][j]))));
            acc[3][j] = fmaf(w0.w, hv.x, fmaf(w1.w, hv.y, fmaf(w2.w, hv.z, fmaf(w3.w, hv.w, acc[3][j]))));
          }
        }
      }
      // pack keys (monotone float map, ~v secondary -> first-index tie-break) and reduce
      unsigned long long best[4];
#pragma unroll
      for (int j = 0; j < 4; ++j) {
        best[j] = 0ull;
#pragma unroll
        for (int vi = 0; vi < 4; ++vi) {
          const int v = blk * 64 + v_col * 4 + vi;
          const float lg = acc[vi][j] + bout[v];
          unsigned u = __float_as_uint(lg);
          u = (u & 0x80000000u) ? ~u : (u | 0x80000000u);
          const unsigned long long key = ((unsigned long long)u << 32) | (unsigned)(~(unsigned)v);
          best[j] = best[j] > key ? best[j] : key;
        }
        unsigned long long o = __shfl_xor(best[j], 16, 64);
        best[j] = best[j] > o ? best[j] : o;
        o = __shfl_xor(best[j], 32, 64);
        best[j] = best[j] > o ? best[j] : o;
      }
      const int lane = tid & 63, wvi = tid >> 6;
      if ((lane >> 4) == 0) {
#pragma unroll
        for (int j = 0; j < 4; ++j) sm.c.red[wvi][(lane & 15) * 4 + j] = best[j];
      }
      __syncthreads();
      if (tid < 64) {
        unsigned long long m0 = sm.c.red[0][tid], m1 = sm.c.red[1][tid];
        unsigned long long m2 = sm.c.red[2][tid], m3 = sm.c.red[3][tid];
        unsigned long long ma = m0 > m1 ? m0 : m1;
        unsigned long long mb = m2 > m3 ? m2 : m3;
        unsigned long long mm = ma > mb ? ma : mb;
        __hip_atomic_fetch_max(&argkey[((t & 1) * 64 + tid) * 8], mm,
                               __ATOMIC_RELAXED, __HIP_MEMORY_SCOPE_AGENT);
      }
    }
    gsync(cnt, gen, mygen);
  }
}

extern "C" void kernel_launch(void* const* d_in, const int* in_sizes, int n_in,
                              void* d_out, int out_size, void* d_ws, size_t ws_size,
                              hipStream_t stream) {
  const float* enc  = (const float*)d_in[0];
  const float* emb  = (const float*)d_in[1];
  const float* Wh   = (const float*)d_in[2];
  const float* bh   = (const float*)d_in[3];
  const float* Wc   = (const float*)d_in[4];
  const float* bc   = (const float*)d_in[5];
  const float* Wih0 = (const float*)d_in[6];
  const float* Whh0 = (const float*)d_in[7];
  const float* bih0 = (const float*)d_in[8];
  const float* bhh0 = (const float*)d_in[9];
  const float* Wih1 = (const float*)d_in[10];
  const float* Whh1 = (const float*)d_in[11];
  const float* bih1 = (const float*)d_in[12];
  const float* bhh1 = (const float*)d_in[13];
  const float* Wout = (const float*)d_in[14];
  const float* bout = (const float*)d_in[15];
  const int* sosp   = (const int*)d_in[16];
  const int* eosp   = (const int*)d_in[17];

  float* ws = (float*)d_ws;
  unsigned long long* argkey =
      (unsigned long long*)((char*)d_ws + (size_t)OFF_FLOAT_END * 4);
  unsigned* bar = (unsigned*)((char*)d_ws + (size_t)OFF_FLOAT_END * 4 + 1024 * 8);
  int* out = (int*)d_out;

  lstm_init_kernel<<<65, NTHR, 0, stream>>>(enc, Wh, bh, Wc, bc, bih0, bhh0,
                                            bih1, bhh1, ws, argkey, bar);
  lstm_transpose_kernel<<<320, NTHR, 0, stream>>>(Wih0, Whh0, Wih1, Whh1, ws);
  lstm_decode_kernel<<<NBLK, NTHR, 0, stream>>>(emb, Wout, bout, sosp, eosp,
                                                ws, argkey, bar, out);
}

// Round 2
// 9914.803 us; speedup vs baseline: 1.2164x; 1.2164x over previous
//
#include <hip/hip_runtime.h>
#include <math.h>

#define NBLK 500
#define NTHR 256
#define TSTEPS 48

// workspace layout (float offsets)
#define OFF_WIH0T 0                         // [512][1024]
#define OFF_WHH0T (OFF_WIH0T + 512*1024)    // [256][1024]
#define OFF_WIH1T (OFF_WHH0T + 256*1024)    // [256][1024]
#define OFF_WHH1T (OFF_WIH1T + 256*1024)    // [256][1024]
#define OFF_BSUM0 (OFF_WHH1T + 256*1024)    // [1024]
#define OFF_BSUM1 (OFF_BSUM0 + 1024)        // [1024]
#define OFF_G0P   (OFF_BSUM1 + 1024)        // [3][64][1024]
#define OFF_G1P   (OFF_G0P + 3*64*1024)     // [2][64][1024]
#define OFF_H0    (OFF_G1P + 2*64*1024)     // [64][256]
#define OFF_H1    (OFF_H0 + 64*256)         // [64][256]
#define OFF_C0    (OFF_H1 + 64*256)         // [2][64][256] (double buffered)
#define OFF_C1    (OFF_C0 + 2*64*256)       // [64][256]
#define OFF_FLOAT_END (OFF_C1 + 64*256)
// then: argkey u64[2][64] padded to 64B stride (1024 u64 slots), then bar u32[2]

// ---- coherent (L2-bypassing sc1, device-visible) accessors for cross-block data ----
__device__ __forceinline__ float ld_coh(const float* p) {
  return __hip_atomic_load((float*)p, __ATOMIC_RELAXED, __HIP_MEMORY_SCOPE_AGENT);
}
__device__ __forceinline__ void st_coh(float* p, float v) {
  __hip_atomic_store(p, v, __ATOMIC_RELAXED, __HIP_MEMORY_SCOPE_AGENT);
}
__device__ __forceinline__ unsigned long long ld_coh64(const unsigned long long* p) {
  return __hip_atomic_load((unsigned long long*)p, __ATOMIC_RELAXED, __HIP_MEMORY_SCOPE_AGENT);
}
__device__ __forceinline__ void st_coh64(unsigned long long* p, unsigned long long v) {
  __hip_atomic_store(p, v, __ATOMIC_RELAXED, __HIP_MEMORY_SCOPE_AGENT);
}
__device__ __forceinline__ float sigf(float x) { return 1.0f / (1.0f + expf(-x)); }

// grid barrier, fully RELAXED (no buffer_wbl2 / buffer_inv — the round-1 release
// fetch_add emitted a per-arrival L2 writeback scan that dominated runtime).
// Sound because ALL cross-block data moves through sc1 (IC-coherent) atomic
// accesses; the explicit per-wave s_waitcnt(0) drains those stores to the
// coherence point before the arrival increment. Monotone counter: no reset, so
// no relaxed-store ordering hazard between counter reset and generation bump.
__device__ __forceinline__ void gsync(unsigned* cnt, unsigned* gen, unsigned& mygen) {
  __asm__ __volatile__("" ::: "memory");
  __builtin_amdgcn_s_waitcnt(0);          // per-wave: drain outstanding sc1 stores/atomics
  __syncthreads();
  if (threadIdx.x == 0) {
    unsigned prev = __hip_atomic_fetch_add(cnt, 1u, __ATOMIC_RELAXED, __HIP_MEMORY_SCOPE_AGENT);
    if (prev == mygen * (unsigned)NBLK + (unsigned)(NBLK - 1)) {
      __hip_atomic_store(gen, mygen + 1u, __ATOMIC_RELAXED, __HIP_MEMORY_SCOPE_AGENT);
    } else {
      while (__hip_atomic_load(gen, __ATOMIC_RELAXED, __HIP_MEMORY_SCOPE_AGENT) <= mygen) {
        __builtin_amdgcn_s_sleep(2);
      }
    }
  }
  ++mygen;
  __asm__ __volatile__("" ::: "memory");
  __syncthreads();
}

// ---- init: h/c initial states, bias sums, argmax keys, barrier ----
__global__ void lstm_init_kernel(const float* enc, const float* Wh, const float* bh,
                                 const float* Wc, const float* bc,
                                 const float* bih0, const float* bhh0,
                                 const float* bih1, const float* bhh1,
                                 float* ws, unsigned long long* argkey, unsigned* bar) {
  const int tid = threadIdx.x, blk = blockIdx.x;
  if (blk < 64) {
    __shared__ float el[256];
    el[tid] = enc[blk * 256 + tid];
    __syncthreads();
    const float4* el4 = (const float4*)el;
    const float4* wh4 = (const float4*)(Wh + tid * 256);
    const float4* wc4 = (const float4*)(Wc + tid * 256);
    float ah = bh[tid], ac = bc[tid];
#pragma unroll 4
    for (int f = 0; f < 64; ++f) {
      float4 x = el4[f], a = wh4[f], b = wc4[f];
      ah = fmaf(a.x, x.x, fmaf(a.y, x.y, fmaf(a.z, x.z, fmaf(a.w, x.w, ah))));
      ac = fmaf(b.x, x.x, fmaf(b.y, x.y, fmaf(b.z, x.z, fmaf(b.w, x.w, ac))));
    }
    ws[OFF_H0 + blk * 256 + tid] = ah;
    ws[OFF_H1 + blk * 256 + tid] = ah;
    ws[OFF_C0 + blk * 256 + tid] = ac;   // parity 0
    ws[OFF_C1 + blk * 256 + tid] = ac;
  } else {
    for (int g = tid; g < 1024; g += 256) {
      ws[OFF_BSUM0 + g] = bih0[g] + bhh0[g];
      ws[OFF_BSUM1 + g] = bih1[g] + bhh1[g];
    }
    for (int i = tid; i < 1024; i += 256) argkey[i] = 0ull;
    if (tid < 2) bar[tid] = 0u;
  }
}

// ---- transpose gate weights to [k][1024] so gate dots are lane-coalesced ----
__global__ void lstm_transpose_kernel(const float* Wih0, const float* Whh0,
                                      const float* Wih1, const float* Whh1, float* ws) {
  __shared__ float t[64][65];
  const int blk = blockIdx.x, tid = threadIdx.x;
  const float* src; float* dst; int C; int tile;
  if (blk < 128)      { src = Wih0; dst = ws + OFF_WIH0T; C = 512; tile = blk; }
  else if (blk < 192) { src = Whh0; dst = ws + OFF_WHH0T; C = 256; tile = blk - 128; }
  else if (blk < 256) { src = Wih1; dst = ws + OFF_WIH1T; C = 256; tile = blk - 192; }
  else                { src = Whh1; dst = ws + OFF_WHH1T; C = 256; tile = blk - 256; }
  const int tpr = C >> 6;
  const int r0 = (tile / tpr) << 6, c0 = (tile % tpr) << 6;
  const int c = tid & 63, w = tid >> 6;
  for (int p = 0; p < 16; ++p) { int r = p * 4 + w; t[r][c] = src[(size_t)(r0 + r) * C + c0 + c]; }
  __syncthreads();
  for (int p = 0; p < 16; ++p) { int cc = p * 4 + w; dst[(size_t)(c0 + cc) * 1024 + r0 + c] = t[c][cc]; }
}

// shared dot: 256-step K, 4 batch accumulators, weights coalesced over lanes
__device__ __forceinline__ void dot256(const float* wp, const float4* xl,
                                       float& a0, float& a1, float& a2, float& a3) {
  a0 = a1 = a2 = a3 = 0.f;
#pragma unroll 16
  for (int k = 0; k < 256; ++k) {
    float wv = wp[(size_t)k * 1024];
    float4 x = xl[k];
    a0 = fmaf(wv, x.x, a0); a1 = fmaf(wv, x.y, a1);
    a2 = fmaf(wv, x.z, a2); a3 = fmaf(wv, x.w, a3);
  }
}

__global__ __launch_bounds__(256, 2) void lstm_decode_kernel(
    const float* __restrict__ emb, const float* __restrict__ Wout,
    const float* __restrict__ bout, const int* __restrict__ sosp,
    const int* __restrict__ eosp, float* __restrict__ ws,
    unsigned long long* __restrict__ argkey, unsigned* __restrict__ bar,
    int* __restrict__ out) {
  const int tid = threadIdx.x;
  const int blk = blockIdx.x;
  __shared__ int tok_s[64];
  __shared__ unsigned long long done_s;
  __shared__ int alldone_s;
  __shared__ union {
    float x4[256 * 4];   // P1/P2: staged x transposed [k][4b]
    struct {             // P3b: Wout chunk row-major [64v][64k]; h1 [64b][64k] k-quad xor b_row
      float w[64 * 64];
      float h[64 * 64];
      unsigned long long red[4][64];
    } c;
  } sm;
  unsigned* cnt = bar; unsigned* gen = bar + 1;
  unsigned mygen = 0;
  const int eos = *eosp;
  const int sos = *sosp;

  for (int t = 0;; ++t) {
    // ---------- preamble: consume step t-1 argmax, update done state, emit token ----------
    if (t == 0) {
      if (tid < 64) tok_s[tid] = sos;
      if (tid == 0) { done_s = 0ull; alldone_s = 0; }
    } else {
      if (tid < 64) {
        unsigned long long key = ld_coh64(&argkey[(((t - 1) & 1) * 64 + tid) * 8]);
        int v = (int)(~(unsigned)key);
        int outv = alldone_s ? 0 : v;                    // all_done BEFORE this step's update
        if (blk == 0) out[tid * TSTEPS + (t - 1)] = outv;
        bool nd = (((done_s >> tid) & 1ull) != 0ull) || (outv == eos);
        unsigned long long m = __ballot(nd);
        if (tid == 0) { done_s = m; if (m == ~0ull) alldone_s = 1; }
        tok_s[tid] = outv;                               // emb[0] is the zero row -> matches ref
      }
    }
    if (t == TSTEPS) break;
    __syncthreads();

    // ---------- P1: layer-0 gate partials. blocks: 16 bgroups x 4 quarters x 3 k-slices ----------
    if (blk < 192) {
      const int ks = blk % 3;
      const int q  = (blk / 3) & 3;
      const int bg = blk / 12;
      float hv[4];
      if (ks < 2) {
        const int kofs = ks * 256 + tid;
#pragma unroll
        for (int j = 0; j < 4; ++j)
          hv[j] = emb[(size_t)tok_s[bg * 4 + j] * 512 + kofs];
      } else {
#pragma unroll
        for (int j = 0; j < 4; ++j)
          hv[j] = ld_coh(&ws[OFF_H0 + (bg * 4 + j) * 256 + tid]);
      }
      ((float4*)sm.x4)[tid] = make_float4(hv[0], hv[1], hv[2], hv[3]);
      __syncthreads();
      const float* wp = ws + (ks == 0 ? OFF_WIH0T
                              : ks == 1 ? (OFF_WIH0T + 256 * 1024)
                                        : OFF_WHH0T) + (q * 256 + tid);
      float a0, a1, a2, a3;
      dot256(wp, (const float4*)sm.x4, a0, a1, a2, a3);
      const int g = q * 256 + tid;
      st_coh(&ws[OFF_G0P + (ks * 64 + bg * 4 + 0) * 1024 + g], a0);
      st_coh(&ws[OFF_G0P + (ks * 64 + bg * 4 + 1) * 1024 + g], a1);
      st_coh(&ws[OFF_G0P + (ks * 64 + bg * 4 + 2) * 1024 + g], a2);
      st_coh(&ws[OFF_G0P + (ks * 64 + bg * 4 + 3) * 1024 + g], a3);
    }
    gsync(cnt, gen, mygen);

    // ---------- P2: h0/c0 update (redundant per q) + layer-1 gate partials ----------
    if (blk < 128) {
      const int ks = blk & 1, q = (blk >> 1) & 3, bg = blk >> 3;
      float hv[4];
      if (ks == 0) {
#pragma unroll
        for (int j = 0; j < 4; ++j) {
          const int b = bg * 4 + j;
          const float* g0 = ws + OFF_G0P;
          float gi = ld_coh(&g0[(b) * 1024 + tid]) + ld_coh(&g0[(64 + b) * 1024 + tid]) +
                     ld_coh(&g0[(128 + b) * 1024 + tid]) + ws[OFF_BSUM0 + tid];
          float gf = ld_coh(&g0[(b) * 1024 + 256 + tid]) + ld_coh(&g0[(64 + b) * 1024 + 256 + tid]) +
                     ld_coh(&g0[(128 + b) * 1024 + 256 + tid]) + ws[OFF_BSUM0 + 256 + tid];
          float gg = ld_coh(&g0[(b) * 1024 + 512 + tid]) + ld_coh(&g0[(64 + b) * 1024 + 512 + tid]) +
                     ld_coh(&g0[(128 + b) * 1024 + 512 + tid]) + ws[OFF_BSUM0 + 512 + tid];
          float go = ld_coh(&g0[(b) * 1024 + 768 + tid]) + ld_coh(&g0[(64 + b) * 1024 + 768 + tid]) +
                     ld_coh(&g0[(128 + b) * 1024 + 768 + tid]) + ws[OFF_BSUM0 + 768 + tid];
          float c  = ld_coh(&ws[OFF_C0 + (t & 1) * 16384 + b * 256 + tid]);
          float cn = sigf(gf) * c + sigf(gi) * tanhf(gg);
          float hn = sigf(go) * tanhf(cn);
          if (q == 0) {
            st_coh(&ws[OFF_H0 + b * 256 + tid], hn);
            st_coh(&ws[OFF_C0 + ((t + 1) & 1) * 16384 + b * 256 + tid], cn);
          }
          hv[j] = hn;
        }
      } else {
#pragma unroll
        for (int j = 0; j < 4; ++j)
          hv[j] = ld_coh(&ws[OFF_H1 + (bg * 4 + j) * 256 + tid]);
      }
      ((float4*)sm.x4)[tid] = make_float4(hv[0], hv[1], hv[2], hv[3]);
      __syncthreads();
      const float* wp = ws + (ks == 0 ? OFF_WIH1T : OFF_WHH1T) + (q * 256 + tid);
      float a0, a1, a2, a3;
      dot256(wp, (const float4*)sm.x4, a0, a1, a2, a3);
      const int g = q * 256 + tid;
      st_coh(&ws[OFF_G1P + (ks * 64 + bg * 4 + 0) * 1024 + g], a0);
      st_coh(&ws[OFF_G1P + (ks * 64 + bg * 4 + 1) * 1024 + g], a1);
      st_coh(&ws[OFF_G1P + (ks * 64 + bg * 4 + 2) * 1024 + g], a2);
      st_coh(&ws[OFF_G1P + (ks * 64 + bg * 4 + 3) * 1024 + g], a3);
    }
    gsync(cnt, gen, mygen);

    // ---------- P3a: h1/c1 update (64 blocks) + reset next-parity argmax keys ----------
    if (blk < 64) {
      const int b = blk;
      const float* g1 = ws + OFF_G1P;
      float gi = ld_coh(&g1[(b) * 1024 + tid]) + ld_coh(&g1[(64 + b) * 1024 + tid]) + ws[OFF_BSUM1 + tid];
      float gf = ld_coh(&g1[(b) * 1024 + 256 + tid]) + ld_coh(&g1[(64 + b) * 1024 + 256 + tid]) + ws[OFF_BSUM1 + 256 + tid];
      float gg = ld_coh(&g1[(b) * 1024 + 512 + tid]) + ld_coh(&g1[(64 + b) * 1024 + 512 + tid]) + ws[OFF_BSUM1 + 512 + tid];
      float go = ld_coh(&g1[(b) * 1024 + 768 + tid]) + ld_coh(&g1[(64 + b) * 1024 + 768 + tid]) + ws[OFF_BSUM1 + 768 + tid];
      float c  = ld_coh(&ws[OFF_C1 + b * 256 + tid]);
      float cn = sigf(gf) * c + sigf(gi) * tanhf(gg);
      float hn = sigf(go) * tanhf(cn);
      st_coh(&ws[OFF_C1 + b * 256 + tid], cn);
      st_coh(&ws[OFF_H1 + b * 256 + tid], hn);
    }
    if (blk == 0 && tid < 64) st_coh64(&argkey[(((t + 1) & 1) * 64 + tid) * 8], 0ull);
    gsync(cnt, gen, mygen);

    // ---------- P3b: logits (all 500 blocks, 64 vocab rows each) + argmax ----------
    {
      const int v_col = tid >> 4, b_row = tid & 15;
      float acc[4][4];
#pragma unroll
      for (int i = 0; i < 4; ++i)
#pragma unroll
        for (int j = 0; j < 4; ++j) acc[i][j] = 0.f;

      for (int kc = 0; kc < 4; ++kc) {
        __syncthreads();
        // stage: Wout chunk row-major [v][k] (coalesced global, conflict-free LDS);
        // h1 as [b][k] with k-quad xor'd by b_row (conflict-free both ways)
#pragma unroll
        for (int p = 0; p < 4; ++p) {
          const int idx = p * 256 + tid;
          const int r = idx >> 4, cq = idx & 15;          // r: v-row / b-row, cq: k-quad
          const float4 wv4 = *(const float4*)&Wout[(size_t)(blk * 64 + r) * 256 + kc * 64 + cq * 4];
          *(float4*)&sm.c.w[r * 64 + cq * 4] = wv4;
          const unsigned long long* hp =
              (const unsigned long long*)&ws[OFF_H1 + r * 256 + kc * 64 + cq * 4];
          float4 hv4;
          ((unsigned long long*)&hv4)[0] = ld_coh64(&hp[0]);
          ((unsigned long long*)&hv4)[1] = ld_coh64(&hp[1]);
          *(float4*)&sm.c.h[r * 64 + ((cq ^ ((r >> 2) & 15)) << 2)] = hv4;
        }
        __syncthreads();
#pragma unroll 4
        for (int k4 = 0; k4 < 16; ++k4) {
          const int kb = k4 * 4;
          float4 wv[4], hv[4];
#pragma unroll
          for (int vi = 0; vi < 4; ++vi)
            wv[vi] = *(const float4*)&sm.c.w[(v_col * 4 + vi) * 64 + kb];   // broadcast (free)
#pragma unroll
          for (int j = 0; j < 4; ++j) {
            const int b = b_row * 4 + j;
            hv[j] = *(const float4*)&sm.c.h[b * 64 + ((k4 ^ b_row) << 2)];
          }
#pragma unroll
          for (int vi = 0; vi < 4; ++vi)
#pragma unroll
            for (int j = 0; j < 4; ++j)
              acc[vi][j] = fmaf(wv[vi].x, hv[j].x,
                           fmaf(wv[vi].y, hv[j].y,
                           fmaf(wv[vi].z, hv[j].z,
                           fmaf(wv[vi].w, hv[j].w, acc[vi][j]))));
        }
      }
      // pack keys (monotone float map, ~v secondary -> first-index tie-break) and reduce
      unsigned long long best[4];
#pragma unroll
      for (int j = 0; j < 4; ++j) {
        best[j] = 0ull;
#pragma unroll
        for (int vi = 0; vi < 4; ++vi) {
          const int v = blk * 64 + v_col * 4 + vi;
          const float lg = acc[vi][j] + bout[v];
          unsigned u = __float_as_uint(lg);
          u = (u & 0x80000000u) ? ~u : (u | 0x80000000u);
          const unsigned long long key = ((unsigned long long)u << 32) | (unsigned)(~(unsigned)v);
          best[j] = best[j] > key ? best[j] : key;
        }
        unsigned long long o = __shfl_xor(best[j], 16, 64);
        best[j] = best[j] > o ? best[j] : o;
        o = __shfl_xor(best[j], 32, 64);
        best[j] = best[j] > o ? best[j] : o;
      }
      const int lane = tid & 63, wvi = tid >> 6;
      if ((lane >> 4) == 0) {
#pragma unroll
        for (int j = 0; j < 4; ++j) sm.c.red[wvi][(lane & 15) * 4 + j] = best[j];
      }
      __syncthreads();
      if (tid < 64) {
        unsigned long long m0 = sm.c.red[0][tid], m1 = sm.c.red[1][tid];
        unsigned long long m2 = sm.c.red[2][tid], m3 = sm.c.red[3][tid];
        unsigned long long ma = m0 > m1 ? m0 : m1;
        unsigned long long mb = m2 > m3 ? m2 : m3;
        unsigned long long mm = ma > mb ? ma : mb;
        __hip_atomic_fetch_max(&argkey[((t & 1) * 64 + tid) * 8], mm,
                               __ATOMIC_RELAXED, __HIP_MEMORY_SCOPE_AGENT);
      }
    }
    gsync(cnt, gen, mygen);
  }
}

extern "C" void kernel_launch(void* const* d_in, const int* in_sizes, int n_in,
                              void* d_out, int out_size, void* d_ws, size_t ws_size,
                              hipStream_t stream) {
  const float* enc  = (const float*)d_in[0];
  const float* emb  = (const float*)d_in[1];
  const float* Wh   = (const float*)d_in[2];
  const float* bh   = (const float*)d_in[3];
  const float* Wc   = (const float*)d_in[4];
  const float* bc   = (const float*)d_in[5];
  const float* Wih0 = (const float*)d_in[6];
  const float* Whh0 = (const float*)d_in[7];
  const float* bih0 = (const float*)d_in[8];
  const float* bhh0 = (const float*)d_in[9];
  const float* Wih1 = (const float*)d_in[10];
  const float* Whh1 = (const float*)d_in[11];
  const float* bih1 = (const float*)d_in[12];
  const float* bhh1 = (const float*)d_in[13];
  const float* Wout = (const float*)d_in[14];
  const float* bout = (const float*)d_in[15];
  const int* sosp   = (const int*)d_in[16];
  const int* eosp   = (const int*)d_in[17];

  float* ws = (float*)d_ws;
  unsigned long long* argkey =
      (unsigned long long*)((char*)d_ws + (size_t)OFF_FLOAT_END * 4);
  unsigned* bar = (unsigned*)((char*)d_ws + (size_t)OFF_FLOAT_END * 4 + 1024 * 8);
  int* out = (int*)d_out;

  lstm_init_kernel<<<65, NTHR, 0, stream>>>(enc, Wh, bh, Wc, bc, bih0, bhh0,
                                            bih1, bhh1, ws, argkey, bar);
  lstm_transpose_kernel<<<320, NTHR, 0, stream>>>(Wih0, Whh0, Wih1, Whh1, ws);
  lstm_decode_kernel<<<NBLK, NTHR, 0, stream>>>(emb, Wout, bout, sosp, eosp,
                                                ws, argkey, bar, out);
}

// Round 3
// 5299.820 us; speedup vs baseline: 2.2756x; 1.8708x over previous
//
#include <hip/hip_runtime.h>
#include <math.h>

#define NBLK 500
#define NTHR 256
#define TSTEPS 48

// ---------------- workspace layout (float offsets) ----------------
#define OFF_WIH0T 0                         // [512][1024]
#define OFF_WHH0T 524288                    // [256][1024]
#define OFF_WIH1T 786432                    // [256][1024]
#define OFF_WHH1T 1048576                   // [256][1024]
#define OFF_BSUM0 1310720                   // [1024]
#define OFF_BSUM1 1311744                   // [1024]
#define OFF_G0P   1312768                   // [6][64][1024]
#define OFF_G1P   1705984                   // [4][64][1024]
#define OFF_H0    1968128                   // [64][256]
#define OFF_H1    1984512                   // [64][256]
#define OFF_C0    2000896                   // [2][64][256] parity double buffer
#define OFF_C1    2033664                   // [64][256]
#define OFF_FLOAT_END 2050048
// bytes after floats: argkey u64[4*64*8] (16384B), key2 u64[64*512] (262144B),
// flags u32[40960] (163840B)

// flag regions (u32 offsets, stride 32 u32 = 128B per flag)
#define FSTR 32
#define FB_P1  0        // 384 flags
#define FB_P2  12288    // 256 flags
#define FB_P3A 20480    // 64 flags
#define FB_ARG 22528    // 512 flags (500 used, 500..511 preset to ~0)
#define FB_RED 38912    // 64 flags
#define NFLAGS 40960

// ---- coherent (sc1, device-visible) accessors for cross-block data ----
__device__ __forceinline__ float ld_coh(const float* p) {
  return __hip_atomic_load((float*)p, __ATOMIC_RELAXED, __HIP_MEMORY_SCOPE_AGENT);
}
__device__ __forceinline__ void st_coh(float* p, float v) {
  __hip_atomic_store(p, v, __ATOMIC_RELAXED, __HIP_MEMORY_SCOPE_AGENT);
}
__device__ __forceinline__ unsigned long long ld_coh64(const unsigned long long* p) {
  return __hip_atomic_load((unsigned long long*)p, __ATOMIC_RELAXED, __HIP_MEMORY_SCOPE_AGENT);
}
__device__ __forceinline__ void st_coh64(unsigned long long* p, unsigned long long v) {
  __hip_atomic_store(p, v, __ATOMIC_RELAXED, __HIP_MEMORY_SCOPE_AGENT);
}
__device__ __forceinline__ unsigned ld_cohu(const unsigned* p) {
  return __hip_atomic_load((unsigned*)p, __ATOMIC_RELAXED, __HIP_MEMORY_SCOPE_AGENT);
}
__device__ __forceinline__ void st_cohu(unsigned* p, unsigned v) {
  __hip_atomic_store(p, v, __ATOMIC_RELAXED, __HIP_MEMORY_SCOPE_AGENT);
}
__device__ __forceinline__ float sigf(float x) { return 1.0f / (1.0f + expf(-x)); }

// post: drain this block's coherent stores (per-wave waitcnt + barrier), then
// thread 0 publishes the flag value (monotone step counter; no resets needed).
__device__ __forceinline__ void post_flag(unsigned* f, unsigned val) {
  __asm__ __volatile__("" ::: "memory");
  __builtin_amdgcn_s_waitcnt(0);
  __syncthreads();
  if (threadIdx.x == 0) st_cohu(f, val);
  __asm__ __volatile__("" ::: "memory");
}

// wave0 lanes poll n (<=64) distinct 128B-strided flag lines; whole block released.
__device__ __forceinline__ void wait_flags(const unsigned* base, int n, unsigned target) {
  if (threadIdx.x < 64) {
    unsigned v = target;
    for (;;) {
      if ((int)threadIdx.x < n) v = ld_cohu(base + threadIdx.x * FSTR);
      if (__all((int)(v >= target))) break;
      __builtin_amdgcn_s_sleep(4);
    }
  }
  __syncthreads();
}

// ---- init: h/c initial states, bias sums, argkey, key2, flags ----
__global__ void lstm_init_kernel(const float* enc, const float* Wh, const float* bh,
                                 const float* Wc, const float* bc,
                                 const float* bih0, const float* bhh0,
                                 const float* bih1, const float* bhh1,
                                 float* ws, unsigned long long* argkey,
                                 unsigned long long* key2, unsigned* flags) {
  const int tid = threadIdx.x, blk = blockIdx.x;
  if (blk < 64) {
    __shared__ float el[256];
    el[tid] = enc[blk * 256 + tid];
    __syncthreads();
    const float4* el4 = (const float4*)el;
    const float4* wh4 = (const float4*)(Wh + tid * 256);
    const float4* wc4 = (const float4*)(Wc + tid * 256);
    float ah = bh[tid], ac = bc[tid];
#pragma unroll 4
    for (int f = 0; f < 64; ++f) {
      float4 x = el4[f], a = wh4[f], b = wc4[f];
      ah = fmaf(a.x, x.x, fmaf(a.y, x.y, fmaf(a.z, x.z, fmaf(a.w, x.w, ah))));
      ac = fmaf(b.x, x.x, fmaf(b.y, x.y, fmaf(b.z, x.z, fmaf(b.w, x.w, ac))));
    }
    ws[OFF_H0 + blk * 256 + tid] = ah;
    ws[OFF_H1 + blk * 256 + tid] = ah;
    ws[OFF_C0 + blk * 256 + tid] = ac;   // parity 0
    ws[OFF_C1 + blk * 256 + tid] = ac;
  } else if (blk == 64) {
    for (int g = tid; g < 1024; g += 256) {
      ws[OFF_BSUM0 + g] = bih0[g] + bhh0[g];
      ws[OFF_BSUM1 + g] = bih1[g] + bhh1[g];
    }
    for (int i = tid; i < 2048; i += 256) argkey[i] = 0ull;
  } else {
    const int base = (blk - 65) * 256 + tid;
    for (int i = base; i < 64 * 512; i += 15 * 256) key2[i] = 0ull;
    for (int i = base; i < NFLAGS; i += 15 * 256) {
      unsigned v = 0u;
      if (i >= FB_ARG && i < FB_RED) {
        const int entry = (i - FB_ARG) >> 5;
        if (entry >= NBLK) v = 0xFFFFFFFFu;   // pad entries always "done"
      }
      flags[i] = v;
    }
  }
}

// ---- transpose gate weights to [k][1024] so gate dots are lane-coalesced ----
__global__ void lstm_transpose_kernel(const float* Wih0, const float* Whh0,
                                      const float* Wih1, const float* Whh1, float* ws) {
  __shared__ float t[64][65];
  const int blk = blockIdx.x, tid = threadIdx.x;
  const float* src; float* dst; int C; int tile;
  if (blk < 128)      { src = Wih0; dst = ws + OFF_WIH0T; C = 512; tile = blk; }
  else if (blk < 192) { src = Whh0; dst = ws + OFF_WHH0T; C = 256; tile = blk - 128; }
  else if (blk < 256) { src = Wih1; dst = ws + OFF_WIH1T; C = 256; tile = blk - 192; }
  else                { src = Whh1; dst = ws + OFF_WHH1T; C = 256; tile = blk - 256; }
  const int tpr = C >> 6;
  const int r0 = (tile / tpr) << 6, c0 = (tile % tpr) << 6;
  const int c = tid & 63, w = tid >> 6;
  for (int p = 0; p < 16; ++p) { int r = p * 4 + w; t[r][c] = src[(size_t)(r0 + r) * C + c0 + c]; }
  __syncthreads();
  for (int p = 0; p < 16; ++p) { int cc = p * 4 + w; dst[(size_t)(c0 + cc) * 1024 + r0 + c] = t[c][cc]; }
}

// 128-step K dot, 4 batch accumulators; deep unroll for outstanding loads
__device__ __forceinline__ void dot128(const float* wp, const float4* xl,
                                       float& a0, float& a1, float& a2, float& a3) {
  a0 = a1 = a2 = a3 = 0.f;
#pragma unroll 32
  for (int k = 0; k < 128; ++k) {
    float wv = wp[(size_t)k * 1024];
    float4 x = xl[k];
    a0 = fmaf(wv, x.x, a0); a1 = fmaf(wv, x.y, a1);
    a2 = fmaf(wv, x.z, a2); a3 = fmaf(wv, x.w, a3);
  }
}

__global__ __launch_bounds__(256, 2) void lstm_decode_kernel(
    const float* __restrict__ emb, const float* __restrict__ Wout,
    const float* __restrict__ bout, const int* __restrict__ sosp,
    const int* __restrict__ eosp, float* __restrict__ ws,
    unsigned long long* __restrict__ argkey, unsigned long long* __restrict__ key2,
    unsigned* __restrict__ flags, int* __restrict__ out) {
  const int tid = threadIdx.x;
  const int blk = blockIdx.x;
  __shared__ int tok_s[64];
  __shared__ unsigned long long done_s;
  __shared__ int alldone_s;
  __shared__ union {
    float x4[128 * 4];   // P1/P2: staged x transposed [k][4b]
    struct {             // P3b: Wout chunk row-major [64v][64k]; h1 [64b][64k] swizzled
      float w[64 * 64];
      float h[64 * 64];
      unsigned long long red[4][64];   // also reused as u64[256] by reducer
    } c;
  } sm;
  const int eos = *eosp;
  const int sos = *sosp;

  for (int t = 0;; ++t) {
    const unsigned T = (unsigned)(t + 1);
    // ---------- preamble: wait prior-step argmax, update done state, emit token ----------
    if (t == 0) {
      if (tid < 64) tok_s[tid] = sos;
      if (tid == 0) { done_s = 0ull; alldone_s = 0; }
    } else {
      wait_flags(flags + FB_RED, 64, (unsigned)t);
      if (tid < 64) {
        unsigned long long key = ld_coh64(&argkey[(((t - 1) & 3) * 64 + tid) * 8]);
        int v = (int)(~(unsigned)key);
        int outv = alldone_s ? 0 : v;                    // all_done BEFORE this step's update
        if (blk == 0) out[tid * TSTEPS + (t - 1)] = outv;
        bool nd = (((done_s >> tid) & 1ull) != 0ull) || (outv == eos);
        unsigned long long m = __ballot(nd);
        if (tid == 0) { done_s = m; if (m == ~0ull) alldone_s = 1; }
        tok_s[tid] = outv;                               // emb[0] is the zero row
      }
    }
    if (t == TSTEPS) break;
    __syncthreads();

    // ---------- P1: layer-0 gate partials. 384 blocks = 16 bg x 4 q x 6 k-slices ----------
    if (blk < 384) {
      const int bg = blk / 24, rem = blk % 24, q = rem / 6, ks = rem % 6;
      if (tid < 128) {
        float hv[4];
#pragma unroll
        for (int j = 0; j < 4; ++j) {
          if (ks < 4) hv[j] = emb[(size_t)tok_s[bg * 4 + j] * 512 + ks * 128 + tid];
          else        hv[j] = ld_coh(&ws[OFF_H0 + (bg * 4 + j) * 256 + (ks - 4) * 128 + tid]);
        }
        ((float4*)sm.x4)[tid] = make_float4(hv[0], hv[1], hv[2], hv[3]);
      }
      __syncthreads();
      const float* wp = ws + (ks < 4 ? OFF_WIH0T + ks * 128 * 1024
                                     : OFF_WHH0T + (ks - 4) * 128 * 1024) + (q * 256 + tid);
      float a0, a1, a2, a3;
      dot128(wp, (const float4*)sm.x4, a0, a1, a2, a3);
      const int g = q * 256 + tid;
      st_coh(&ws[OFF_G0P + (size_t)(ks * 64 + bg * 4 + 0) * 1024 + g], a0);
      st_coh(&ws[OFF_G0P + (size_t)(ks * 64 + bg * 4 + 1) * 1024 + g], a1);
      st_coh(&ws[OFF_G0P + (size_t)(ks * 64 + bg * 4 + 2) * 1024 + g], a2);
      st_coh(&ws[OFF_G0P + (size_t)(ks * 64 + bg * 4 + 3) * 1024 + g], a3);
      post_flag(flags + FB_P1 + blk * FSTR, T);
    }

    // ---------- P2: h0/c0 update + layer-1 gate partials. 256 blocks = 16 bg x 4 q x 4 ks ----------
    if (blk < 256) {
      const int bg = blk >> 4, q = (blk >> 2) & 3, ks = blk & 3;
      wait_flags(flags + FB_P1 + bg * 24 * FSTR, 24, T);
      if (ks < 2) {
        // compute h0 for this bg's 4 batches, k-half ks (redundant across q; q==0 stores)
#pragma unroll
        for (int u = 0; u < 2; ++u) {
          const int idx = tid * 2 + u;
          const int bl = idx >> 7, k = idx & 127;
          const int b = bg * 4 + bl, h = ks * 128 + k;
          float gi = 0.f, gf = 0.f, gg = 0.f, go = 0.f;
#pragma unroll
          for (int s = 0; s < 6; ++s) {
            const float* gp = ws + OFF_G0P + (size_t)(s * 64 + b) * 1024;
            gi += ld_coh(&gp[h]);       gf += ld_coh(&gp[256 + h]);
            gg += ld_coh(&gp[512 + h]); go += ld_coh(&gp[768 + h]);
          }
          gi += ws[OFF_BSUM0 + h];       gf += ws[OFF_BSUM0 + 256 + h];
          gg += ws[OFF_BSUM0 + 512 + h]; go += ws[OFF_BSUM0 + 768 + h];
          const float c  = ld_coh(&ws[OFF_C0 + (t & 1) * 16384 + b * 256 + h]);
          const float cn = sigf(gf) * c + sigf(gi) * tanhf(gg);
          const float hn = sigf(go) * tanhf(cn);
          if (q == 0) {
            st_coh(&ws[OFF_H0 + b * 256 + h], hn);
            st_coh(&ws[OFF_C0 + ((t + 1) & 1) * 16384 + b * 256 + h], cn);
          }
          sm.x4[k * 4 + bl] = hn;
        }
      } else {
        if (tid < 128) {
          float hv[4];
#pragma unroll
          for (int j = 0; j < 4; ++j)
            hv[j] = ld_coh(&ws[OFF_H1 + (bg * 4 + j) * 256 + (ks - 2) * 128 + tid]);
          ((float4*)sm.x4)[tid] = make_float4(hv[0], hv[1], hv[2], hv[3]);
        }
      }
      __syncthreads();
      const float* wp = ws + (ks < 2 ? OFF_WIH1T + ks * 128 * 1024
                                     : OFF_WHH1T + (ks - 2) * 128 * 1024) + (q * 256 + tid);
      float a0, a1, a2, a3;
      dot128(wp, (const float4*)sm.x4, a0, a1, a2, a3);
      const int g = q * 256 + tid;
      st_coh(&ws[OFF_G1P + (size_t)(ks * 64 + bg * 4 + 0) * 1024 + g], a0);
      st_coh(&ws[OFF_G1P + (size_t)(ks * 64 + bg * 4 + 1) * 1024 + g], a1);
      st_coh(&ws[OFF_G1P + (size_t)(ks * 64 + bg * 4 + 2) * 1024 + g], a2);
      st_coh(&ws[OFF_G1P + (size_t)(ks * 64 + bg * 4 + 3) * 1024 + g], a3);
      post_flag(flags + FB_P2 + blk * FSTR, T);
    }

    // ---------- P3a: h1/c1 update (64 blocks, one batch each) + argkey reset ----------
    if (blk < 64) {
      wait_flags(flags + FB_P2 + (blk >> 2) * 16 * FSTR, 16, T);
      const int b = blk, h = tid;
      float gi = 0.f, gf = 0.f, gg = 0.f, go = 0.f;
#pragma unroll
      for (int s = 0; s < 4; ++s) {
        const float* gp = ws + OFF_G1P + (size_t)(s * 64 + b) * 1024;
        gi += ld_coh(&gp[h]);       gf += ld_coh(&gp[256 + h]);
        gg += ld_coh(&gp[512 + h]); go += ld_coh(&gp[768 + h]);
      }
      gi += ws[OFF_BSUM1 + h];       gf += ws[OFF_BSUM1 + 256 + h];
      gg += ws[OFF_BSUM1 + 512 + h]; go += ws[OFF_BSUM1 + 768 + h];
      const float c  = ld_coh(&ws[OFF_C1 + b * 256 + h]);
      const float cn = sigf(gf) * c + sigf(gi) * tanhf(gg);
      const float hn = sigf(go) * tanhf(cn);
      st_coh(&ws[OFF_C1 + b * 256 + h], cn);
      st_coh(&ws[OFF_H1 + b * 256 + h], hn);
      if (tid == 0) st_coh64(&argkey[(((t + 1) & 3) * 64 + b) * 8], 0ull);
      post_flag(flags + FB_P3A + blk * FSTR, T);
    }

    // ---------- P3b: logits (all 500 blocks, 64 vocab rows each) + per-block argmax ----------
    {
      const int v_col = tid >> 4, b_row = tid & 15;
      // prefetch Wout kc=0 (independent of h1) before the wait
      float4 wpre[4];
#pragma unroll
      for (int p = 0; p < 4; ++p) {
        const int idx = p * 256 + tid, r = idx >> 4, cq = idx & 15;
        wpre[p] = *(const float4*)&Wout[(size_t)(blk * 64 + r) * 256 + cq * 4];
      }
      wait_flags(flags + FB_P3A, 64, T);
      float4 hpre[4];
#pragma unroll
      for (int p = 0; p < 4; ++p) {
        const int idx = p * 256 + tid, r = idx >> 4, cq = idx & 15;
        const unsigned long long* hp =
            (const unsigned long long*)&ws[OFF_H1 + r * 256 + cq * 4];
        ((unsigned long long*)&hpre[p])[0] = ld_coh64(&hp[0]);
        ((unsigned long long*)&hpre[p])[1] = ld_coh64(&hp[1]);
      }
      float acc[4][4];
#pragma unroll
      for (int i = 0; i < 4; ++i)
#pragma unroll
        for (int j = 0; j < 4; ++j) acc[i][j] = 0.f;

      for (int kc = 0; kc < 4; ++kc) {
        __syncthreads();
#pragma unroll
        for (int p = 0; p < 4; ++p) {
          const int idx = p * 256 + tid, r = idx >> 4, cq = idx & 15;
          *(float4*)&sm.c.w[r * 64 + cq * 4] = wpre[p];
          *(float4*)&sm.c.h[r * 64 + ((cq ^ ((r >> 2) & 15)) << 2)] = hpre[p];
        }
        __syncthreads();
        if (kc < 3) {
#pragma unroll
          for (int p = 0; p < 4; ++p) {
            const int idx = p * 256 + tid, r = idx >> 4, cq = idx & 15;
            wpre[p] = *(const float4*)&Wout[(size_t)(blk * 64 + r) * 256 + (kc + 1) * 64 + cq * 4];
            const unsigned long long* hp =
                (const unsigned long long*)&ws[OFF_H1 + r * 256 + (kc + 1) * 64 + cq * 4];
            ((unsigned long long*)&hpre[p])[0] = ld_coh64(&hp[0]);
            ((unsigned long long*)&hpre[p])[1] = ld_coh64(&hp[1]);
          }
        }
#pragma unroll 4
        for (int k4 = 0; k4 < 16; ++k4) {
          const int kb = k4 * 4;
          float4 wv[4], hv[4];
#pragma unroll
          for (int vi = 0; vi < 4; ++vi)
            wv[vi] = *(const float4*)&sm.c.w[(v_col * 4 + vi) * 64 + kb];   // broadcast
#pragma unroll
          for (int j = 0; j < 4; ++j) {
            const int b = b_row * 4 + j;
            hv[j] = *(const float4*)&sm.c.h[b * 64 + ((k4 ^ b_row) << 2)];
          }
#pragma unroll
          for (int vi = 0; vi < 4; ++vi)
#pragma unroll
            for (int j = 0; j < 4; ++j)
              acc[vi][j] = fmaf(wv[vi].x, hv[j].x,
                           fmaf(wv[vi].y, hv[j].y,
                           fmaf(wv[vi].z, hv[j].z,
                           fmaf(wv[vi].w, hv[j].w, acc[vi][j]))));
        }
      }
      // pack keys (monotone float map, ~v secondary -> first-index tie-break), reduce in-block
      unsigned long long best[4];
#pragma unroll
      for (int j = 0; j < 4; ++j) {
        best[j] = 0ull;
#pragma unroll
        for (int vi = 0; vi < 4; ++vi) {
          const int v = blk * 64 + v_col * 4 + vi;
          const float lg = acc[vi][j] + bout[v];
          unsigned u = __float_as_uint(lg);
          u = (u & 0x80000000u) ? ~u : (u | 0x80000000u);
          const unsigned long long key = ((unsigned long long)u << 32) | (unsigned)(~(unsigned)v);
          best[j] = best[j] > key ? best[j] : key;
        }
        unsigned long long o = __shfl_xor(best[j], 16, 64);
        best[j] = best[j] > o ? best[j] : o;
        o = __shfl_xor(best[j], 32, 64);
        best[j] = best[j] > o ? best[j] : o;
      }
      const int lane = tid & 63, wvi = tid >> 6;
      if ((lane >> 4) == 0) {
#pragma unroll
        for (int j = 0; j < 4; ++j) sm.c.red[wvi][(lane & 15) * 4 + j] = best[j];
      }
      __syncthreads();
      if (tid < 64) {
        unsigned long long m0 = sm.c.red[0][tid], m1 = sm.c.red[1][tid];
        unsigned long long m2 = sm.c.red[2][tid], m3 = sm.c.red[3][tid];
        unsigned long long ma = m0 > m1 ? m0 : m1;
        unsigned long long mb = m2 > m3 ? m2 : m3;
        unsigned long long mm = ma > mb ? ma : mb;
        st_coh64(&key2[(size_t)tid * 512 + blk], mm);   // contention-free scatter
      }
      post_flag(flags + FB_ARG + blk * FSTR, T);
    }

    // ---------- reducer: 64 blocks (one per batch) fold 500 partial argmaxes ----------
    if (blk < 64) {
      for (;;) {
        int ok = (ld_cohu(flags + FB_ARG + tid * FSTR) >= T) &&
                 (ld_cohu(flags + FB_ARG + (tid + 256) * FSTR) >= T);
        if (__syncthreads_and(ok)) break;
        __builtin_amdgcn_s_sleep(4);
      }
      unsigned long long a  = ld_coh64(&key2[(size_t)blk * 512 + tid]);
      unsigned long long b2 = ld_coh64(&key2[(size_t)blk * 512 + tid + 256]);
      unsigned long long m  = a > b2 ? a : b2;
      unsigned long long* red64 = (unsigned long long*)sm.c.red;
      red64[tid] = m;
      __syncthreads();
      if (tid < 64) {
        unsigned long long v = red64[tid];
        unsigned long long w1 = red64[tid + 64];  v = v > w1 ? v : w1;
        w1 = red64[tid + 128]; v = v > w1 ? v : w1;
        w1 = red64[tid + 192]; v = v > w1 ? v : w1;
#pragma unroll
        for (int off = 32; off >= 1; off >>= 1) {
          unsigned long long o = __shfl_xor(v, off, 64);
          v = v > o ? v : o;
        }
        if (tid == 0) st_coh64(&argkey[((t & 3) * 64 + blk) * 8], v);
      }
      post_flag(flags + FB_RED + blk * FSTR, T);
    }
  }
}

extern "C" void kernel_launch(void* const* d_in, const int* in_sizes, int n_in,
                              void* d_out, int out_size, void* d_ws, size_t ws_size,
                              hipStream_t stream) {
  const float* enc  = (const float*)d_in[0];
  const float* emb  = (const float*)d_in[1];
  const float* Wh   = (const float*)d_in[2];
  const float* bh   = (const float*)d_in[3];
  const float* Wc   = (const float*)d_in[4];
  const float* bc   = (const float*)d_in[5];
  const float* Wih0 = (const float*)d_in[6];
  const float* Whh0 = (const float*)d_in[7];
  const float* bih0 = (const float*)d_in[8];
  const float* bhh0 = (const float*)d_in[9];
  const float* Wih1 = (const float*)d_in[10];
  const float* Whh1 = (const float*)d_in[11];
  const float* bih1 = (const float*)d_in[12];
  const float* bhh1 = (const float*)d_in[13];
  const float* Wout = (const float*)d_in[14];
  const float* bout = (const float*)d_in[15];
  const int* sosp   = (const int*)d_in[16];
  const int* eosp   = (const int*)d_in[17];

  float* ws = (float*)d_ws;
  char* base = (char*)d_ws + (size_t)OFF_FLOAT_END * 4;
  unsigned long long* argkey = (unsigned long long*)base;            // 16384 B
  unsigned long long* key2   = (unsigned long long*)(base + 16384);  // 262144 B
  unsigned* flags            = (unsigned*)(base + 16384 + 262144);   // 163840 B
  int* out = (int*)d_out;

  lstm_init_kernel<<<80, NTHR, 0, stream>>>(enc, Wh, bh, Wc, bc, bih0, bhh0,
                                            bih1, bhh1, ws, argkey, key2, flags);
  lstm_transpose_kernel<<<320, NTHR, 0, stream>>>(Wih0, Whh0, Wih1, Whh1, ws);
  lstm_decode_kernel<<<NBLK, NTHR, 0, stream>>>(emb, Wout, bout, sosp, eosp,
                                                ws, argkey, key2, flags, out);
}